// Round 10
// baseline (118.216 us; speedup 1.0000x reference)
//
#include <hip/hip_runtime.h>
#include <math.h>

// NGRU via MFMA, R10 = R9 + x-in-registers + cross-barrier MFMA split.
// Only layer 1 of the 2 parallel GRU layers contributes (reference returns
// h_final[-1]); layer 0 is skipped.
//
// Shapes: x (64,48,256,64) f32; Wih/Whh (2,192,64); bih/bhh (2,192).
// rows = B*N = 16384 independent GRU sequences, T=48, H=64.
//
// Structure: 512 blocks x 256 threads (4 waves), 32 rows/block, 2 blocks/CU.
// Wave nw owns output columns j in [16nw,16nw+16) for ALL FOUR gates
// (r, z, gin, ghn) -> gate epilogue fully register-local. fp16 single-product
// MFMA (R9-verified: absmax unchanged; matmul precision is not the error term).
//
// R10 vs R9 (attacking the post-barrier LDS burst = critical path):
//  * x is NOT recurrent -> per-thread x A-fragments live in REGISTERS
//    (loaded during step t, converted via pkh2 at step tail). LDS is h-only
//    (9.2 KB): post-barrier ds_read_b128 burst halves (8 -> 4 per wave).
//  * MFMA phase SPLIT across the barrier: the 12 x-part MFMAs of step t+1
//    (r,z,gin chains, C = bias operand) run BEFORE the barrier, overlapping
//    the other barrier-domain's post-barrier phase; only the 12 h-part
//    MFMAs (r,z,ghn) remain post-barrier.
//  * Bias as MFMA C-operand: deletes the 32 acc-init v_movs per step.
//  * Unrolled-by-2 loop with named accA/accB (no runtime-indexed acc arrays
//    -> no scratch; rule-#20).
// Chain order per acc unchanged (bias, Wi.k0, Wi.k32, Wh.k0, Wh.k32) ->
// bit-identical numerics to R9.
// waves_per_eu(2,2): full 256-VGPR budget at the grid-fixed 2-blocks/CU
// residency (R7/R8 lesson: without the clamp the allocator targets 4
// waves/EU and spills; verify WRITE_SIZE stays 4 MB).

#define TT 48
#define HH 64
#define GG 192
#define NN 256
#define RPB 32          // rows per block
#define NTHREADS 256    // 4 waves
#define HK 72           // h row stride in halfs (64 + 8 pad)
#define HBUF (RPB*HK)   // 2304 halfs per h buffer

typedef _Float16 h8 __attribute__((ext_vector_type(8)));   // 8 fp16 (4 VGPRs)
typedef __attribute__((ext_vector_type(4))) float f32x4;   // MFMA accum
typedef __attribute__((ext_vector_type(4))) unsigned u32x4;

__device__ __forceinline__ float sigm(float v) {
    return __builtin_amdgcn_rcpf(1.f + __expf(-v));
}
__device__ __forceinline__ float tanh_f(float v) {
    float a = fabsf(v);
    float e = __expf(2.f * a);
    float t = 1.f - 2.f * __builtin_amdgcn_rcpf(e + 1.f);
    return v < 0.f ? -t : t;
}
// pack 2 f32 -> dword of 2 fp16 (RNE)
__device__ __forceinline__ unsigned pkh2(float a, float b) {
    union { _Float16 h[2]; unsigned u; } c;
    c.h[0] = (_Float16)a; c.h[1] = (_Float16)b;
    return c.u;
}
// 8 consecutive f32 (two float4) -> one h8 fragment, k-ascending
__device__ __forceinline__ h8 cvt_frag(float4 a, float4 b) {
    u32x4 w = {pkh2(a.x, a.y), pkh2(a.z, a.w),
               pkh2(b.x, b.y), pkh2(b.z, b.w)};
    return __builtin_bit_cast(h8, w);
}

#define MF(A, B, C) __builtin_amdgcn_mfma_f32_16x16x32_f16(A, B, C, 0, 0, 0)

__global__ __launch_bounds__(NTHREADS)
__attribute__((amdgpu_waves_per_eu(2, 2)))
void ngru_mfma10(const float* __restrict__ x,
                 const float* __restrict__ Wih,
                 const float* __restrict__ Whh,
                 const float* __restrict__ bih,
                 const float* __restrict__ bhh,
                 float* __restrict__ out)
{
    extern __shared__ __align__(16) _Float16 lds_h[];  // 2 x HBUF halfs (h only)

    const int tid  = threadIdx.x;
    const int lane = tid & 63;
    const int nw   = tid >> 6;          // wave 0..3 -> j slice [16nw,16nw+16)
    const int c0   = lane & 15;         // C col within tile / A row index
    const int rq   = lane >> 4;         // quarter-wave
    const int j    = nw * 16 + c0;

    const int grow0 = blockIdx.x * RPB;
    const int bb    = grow0 / NN;
    const int n0    = grow0 % NN;

    const float* Wi = Wih + GG * HH;    // layer 1
    const float* Wh = Whh + GG * HH;

    // ---- B fragments (fp16) in registers ----
    // X slots g*2+kt (0..5) from Wi gate g; H slots 6+g*2+kt (6..11) from Wh.
    // gates g: 0=r, 1=z, 2=n.
    h8 Bf[12];
    #pragma unroll
    for (int g = 0; g < 3; ++g) {
        #pragma unroll
        for (int kt = 0; kt < 2; ++kt) {
            const float* si = Wi + (g * 64 + j) * HH + kt * 32 + rq * 8;
            const float* sh = Wh + (g * 64 + j) * HH + kt * 32 + rq * 8;
            h8 fi, fh;
            #pragma unroll
            for (int q = 0; q < 8; ++q) {
                fi[q] = (_Float16)si[q];
                fh[q] = (_Float16)sh[q];
            }
            Bf[g * 2 + kt]     = fi;
            Bf[6 + g * 2 + kt] = fh;
        }
    }

    // ---- biases as MFMA C-operands (constant across a tile's 4 C-regs) ----
    const float brz  = bih[GG + j]      + bhh[GG + j];
    const float bzz  = bih[GG + 64 + j] + bhh[GG + 64 + j];
    const float bin_ = bih[GG + 128 + j];
    const float bhn_ = bhh[GG + 128 + j];
    const f32x4 BIASr = {brz,  brz,  brz,  brz };
    const f32x4 BIASz = {bzz,  bzz,  bzz,  bzz };
    const f32x4 BIASi = {bin_, bin_, bin_, bin_};
    const f32x4 BIASh = {bhn_, bhn_, bhn_, bhn_};

    // ---- zero h buffer 0 ----
    for (int idx = tid; idx < HBUF / 8; idx += NTHREADS)
        *(u32x4*)(lds_h + idx * 8) = (u32x4){0u, 0u, 0u, 0u};

    // ---- prologue: x(0) frags + x-part MFMAs for t=0 into accA ----
    f32x4 accA[2][4], accB[2][4];
    {
        const float* xb = x + ((size_t)(bb * TT) * NN + n0) * HH;
        h8 Xf[2][2];
        #pragma unroll
        for (int m = 0; m < 2; ++m)
            #pragma unroll
            for (int kt = 0; kt < 2; ++kt) {
                const float* s_ = xb + (m * 16 + c0) * HH + kt * 32 + rq * 8;
                Xf[m][kt] = cvt_frag(*(const float4*)s_, *(const float4*)(s_ + 4));
            }
        #pragma unroll
        for (int m = 0; m < 2; ++m) {
            accA[m][0] = MF(Xf[m][0], Bf[0], BIASr);
            accA[m][0] = MF(Xf[m][1], Bf[1], accA[m][0]);
            accA[m][1] = MF(Xf[m][0], Bf[2], BIASz);
            accA[m][1] = MF(Xf[m][1], Bf[3], accA[m][1]);
            accA[m][2] = MF(Xf[m][0], Bf[4], BIASi);
            accA[m][2] = MF(Xf[m][1], Bf[5], accA[m][2]);
        }
    }

    float hreg[2][4];
    #pragma unroll
    for (int m = 0; m < 2; ++m)
        #pragma unroll
        for (int r = 0; r < 4; ++r) hreg[m][r] = 0.f;

    __syncthreads();   // buf0 h zeros visible

    // One BODY per step; ACCC = this step's acc (x-part already done),
    // ACCN = next step's acc (x-part built pre-barrier at the tail).
#define BODY(ACCC, ACCN, T)                                                    \
    {                                                                          \
        const int t_ = (T);                                                    \
        _Float16* cur = lds_h + (t_ & 1) * HBUF;                               \
        _Float16* nxt = lds_h + ((t_ & 1) ^ 1) * HBUF;                         \
        const bool hasNext = (t_ + 1 < TT);                                    \
        /* h-part A reads: the critical path -> issue first */                 \
        h8 Hf[2][2];                                                           \
        _Pragma("unroll") for (int m = 0; m < 2; ++m)                          \
            _Pragma("unroll") for (int kt = 0; kt < 2; ++kt)                   \
                Hf[m][kt] = *(const h8*)(cur + (m*16 + c0)*HK + kt*32 + rq*8); \
        /* x(t+1) global prefetch (vmcnt-only; doesn't block h-MFMAs) */       \
        float4 pa[2][2], pb[2][2];                                             \
        if (hasNext) {                                                         \
            const float* xb = x + ((size_t)(bb*TT + t_ + 1)*NN + n0)*HH;       \
            _Pragma("unroll") for (int m = 0; m < 2; ++m)                      \
                _Pragma("unroll") for (int kt = 0; kt < 2; ++kt) {             \
                    const float* s_ = xb + (m*16 + c0)*HH + kt*32 + rq*8;      \
                    pa[m][kt] = *(const float4*)s_;                            \
                    pb[m][kt] = *(const float4*)(s_ + 4);                      \
                }                                                              \
        }                                                                      \
        /* h-part MFMAs (post-barrier phase) */                                \
        __builtin_amdgcn_s_setprio(1);                                         \
        _Pragma("unroll") for (int m = 0; m < 2; ++m) {                        \
            ACCC[m][0] = MF(Hf[m][0], Bf[6],  ACCC[m][0]);                     \
            ACCC[m][0] = MF(Hf[m][1], Bf[7],  ACCC[m][0]);                     \
            ACCC[m][1] = MF(Hf[m][0], Bf[8],  ACCC[m][1]);                     \
            ACCC[m][1] = MF(Hf[m][1], Bf[9],  ACCC[m][1]);                     \
            ACCC[m][3] = MF(Hf[m][0], Bf[10], BIASh);                          \
            ACCC[m][3] = MF(Hf[m][1], Bf[11], ACCC[m][3]);                     \
        }                                                                      \
        __builtin_amdgcn_s_setprio(0);                                         \
        /* epilogue: register-local gates; h -> nxt buffer */                  \
        _Pragma("unroll") for (int m = 0; m < 2; ++m) {                        \
            _Pragma("unroll") for (int r = 0; r < 4; ++r) {                    \
                const int row = m * 16 + rq * 4 + r;                           \
                float rg = sigm(ACCC[m][0][r]);                                \
                float zg = sigm(ACCC[m][1][r]);                                \
                float ng = tanh_f(fmaf(rg, ACCC[m][3][r], ACCC[m][2][r]));     \
                float hn = fmaf(zg, hreg[m][r] - ng, ng);                      \
                hreg[m][r] = hn;                                               \
                if (hasNext)                                                   \
                    nxt[row * HK + j] = (_Float16)hn;   /* ds_write_b16 */     \
            }                                                                  \
        }                                                                      \
        if (hasNext) {                                                         \
            /* cvt x(t+1) (vmcnt drained; loads issued ~a full phase ago) */   \
            h8 Xf[2][2];                                                       \
            _Pragma("unroll") for (int m = 0; m < 2; ++m)                      \
                _Pragma("unroll") for (int kt = 0; kt < 2; ++kt)               \
                    Xf[m][kt] = cvt_frag(pa[m][kt], pb[m][kt]);                \
            /* PRE-barrier x-part MFMAs for t+1 (overlap other domain) */      \
            __builtin_amdgcn_s_setprio(1);                                     \
            _Pragma("unroll") for (int m = 0; m < 2; ++m) {                    \
                ACCN[m][0] = MF(Xf[m][0], Bf[0], BIASr);                       \
                ACCN[m][0] = MF(Xf[m][1], Bf[1], ACCN[m][0]);                  \
                ACCN[m][1] = MF(Xf[m][0], Bf[2], BIASz);                       \
                ACCN[m][1] = MF(Xf[m][1], Bf[3], ACCN[m][1]);                  \
                ACCN[m][2] = MF(Xf[m][0], Bf[4], BIASi);                       \
                ACCN[m][2] = MF(Xf[m][1], Bf[5], ACCN[m][2]);                  \
            }                                                                  \
            __builtin_amdgcn_s_setprio(0);                                     \
            __syncthreads();   /* nxt h ready; next step may read */           \
        }                                                                      \
    }

    for (int tt = 0; tt < TT; tt += 2) {
        BODY(accA, accB, tt);
        BODY(accB, accA, tt + 1);
    }
#undef BODY

    #pragma unroll
    for (int m = 0; m < 2; ++m)
        #pragma unroll
        for (int r = 0; r < 4; ++r)
            out[(size_t)(grow0 + m * 16 + rq * 4 + r) * HH + j] = hreg[m][r];
}

extern "C" void kernel_launch(void* const* d_in, const int* in_sizes, int n_in,
                              void* d_out, int out_size, void* d_ws, size_t ws_size,
                              hipStream_t stream) {
    const float* x   = (const float*)d_in[0];
    const float* Wih = (const float*)d_in[1];
    const float* Whh = (const float*)d_in[2];
    const float* bih = (const float*)d_in[3];
    const float* bhh = (const float*)d_in[4];
    float* out = (float*)d_out;

    const int lds_bytes = 2 * HBUF * (int)sizeof(_Float16);   // 9,216 B
    (void)hipFuncSetAttribute((const void*)ngru_mfma10,
                        hipFuncAttributeMaxDynamicSharedMemorySize, lds_bytes);

    dim3 grid(16384 / RPB);     // 512 blocks, 2 per CU
    dim3 block(NTHREADS);
    ngru_mfma10<<<grid, block, lds_bytes, stream>>>(x, Wih, Whh, bih, bhh, out);
}

// Round 11
// 74.137 us; speedup vs baseline: 1.5946x; 1.5946x over previous
//
#include <hip/hip_runtime.h>
#include <math.h>

// NGRU via MFMA, R11 = R9 base + {bias-in-C, paired h-writes, early x-stage}.
// Only layer 1 of the 2 parallel GRU layers contributes (reference returns
// h_final[-1]); layer 0 is skipped.
//
// Shapes: x (64,48,256,64) f32; Wih/Whh (2,192,64); bih/bhh (2,192).
// rows = B*N = 16384 independent GRU sequences, T=48, H=64.
//
// Structure (R9-proven): 512 blocks x 256 threads (4 waves), 32 rows/block,
// 2 blocks/CU (2 barrier domains). Wave nw owns output columns
// j in [16nw,16nw+16) for ALL FOUR gates (r, z, gin, ghn) -> gate epilogue
// fully register-local. fp16 single-product MFMA (R9-verified: absmax
// unchanged; matmul precision is not the error term).
// A = [x_t | h_{t-1}] fp16 [32][AK=136], ping-ponged -> ONE barrier/step.
// x staged once in LDS (R7/R8/R10 proved per-wave x-in-registers loses:
// 4x redundant loads + allocator sinks the prefetch -> latency exposed).
//
// R11 deltas vs R9 (all numerics bit-identical):
//  * bias as MFMA C-operand of each gate chain's first MFMA (-32 v_movs).
//  * paired h-writes: even lanes write m=0 rows, odd lanes m=1 rows, as
//    shfl_xor(1)-packed dwords -> 4 ds_write_b32 (~2-way) instead of
//    8 ds_write_b16 (~4-way).
//  * x(t+1) cvt+stage BEFORE the epilogue (vmcnt long drained; load regs
//    die earlier; x reaches LDS sooner).
// waves_per_eu(2,2): full 256-VGPR budget at grid-fixed 2-blocks/CU.

#define TT 48
#define HH 64
#define GG 192
#define NN 256
#define RPB 32          // rows per block
#define NTHREADS 256    // 4 waves
#define AK 136          // A row stride in halfs (128 + 8 pad; 16B-aligned rows)
#define HBUF (RPB*AK)   // halfs per A buffer (4352)

typedef _Float16 h8 __attribute__((ext_vector_type(8)));   // 8 fp16 (4 VGPRs)
typedef __attribute__((ext_vector_type(4))) float f32x4;   // MFMA accum
typedef __attribute__((ext_vector_type(4))) unsigned u32x4;

__device__ __forceinline__ float sigm(float v) {
    return __builtin_amdgcn_rcpf(1.f + __expf(-v));
}
__device__ __forceinline__ float tanh_f(float v) {
    float a = fabsf(v);
    float e = __expf(2.f * a);
    float t = 1.f - 2.f * __builtin_amdgcn_rcpf(e + 1.f);
    return v < 0.f ? -t : t;
}
// pack 2 f32 -> dword of 2 fp16 (RNE)
__device__ __forceinline__ unsigned pkh2(float a, float b) {
    union { _Float16 h[2]; unsigned u; } c;
    c.h[0] = (_Float16)a; c.h[1] = (_Float16)b;
    return c.u;
}

#define MF(A, B, C) __builtin_amdgcn_mfma_f32_16x16x32_f16(A, B, C, 0, 0, 0)

__global__ __launch_bounds__(NTHREADS)
__attribute__((amdgpu_waves_per_eu(2, 2)))
void ngru_mfma11(const float* __restrict__ x,
                 const float* __restrict__ Wih,
                 const float* __restrict__ Whh,
                 const float* __restrict__ bih,
                 const float* __restrict__ bhh,
                 float* __restrict__ out)
{
    extern __shared__ __align__(16) _Float16 lds_h[];  // 2 x HBUF halfs

    const int tid  = threadIdx.x;
    const int lane = tid & 63;
    const int nw   = tid >> 6;          // wave 0..3 -> j slice [16nw,16nw+16)
    const int c0   = lane & 15;         // C col within tile / A row index
    const int rq   = lane >> 4;         // quarter-wave
    const int j    = nw * 16 + c0;
    const bool odd = (c0 & 1);

    const int grow0 = blockIdx.x * RPB;
    const int bb    = grow0 / NN;
    const int n0    = grow0 % NN;

    const float* Wi = Wih + GG * HH;    // layer 1
    const float* Wh = Whh + GG * HH;

    // ---- B fragments in registers: 12 kt-slots (zero tiles skipped) ----
    // slot: r -> 0..3 (kt0,1 = Wi; kt2,3 = Wh); z -> 4..7 (same);
    //       gin -> 8,9 (Wi, A kt0,1); ghn -> 10,11 (Wh, A kt2,3).
    h8 Bf[12];
    #pragma unroll
    for (int g = 0; g < 4; ++g) {
        const int ktlo = (g == 3) ? 2 : 0;
        const int kthi = (g == 2) ? 2 : 4;
        #pragma unroll
        for (int kt = ktlo; kt < kthi; ++kt) {
            const int slot = (g < 2) ? g * 4 + kt : 8 + (g - 2) * 2 + (kt & 1);
            const bool isWi = (kt < 2);
            const int gbase = (g >= 2) ? 2 : g;
            const float* src = (isWi ? Wi : Wh)
                             + (gbase * 64 + j) * HH + (kt & 1) * 32 + rq * 8;
            h8 f;
            #pragma unroll
            for (int q = 0; q < 8; ++q) f[q] = (_Float16)src[q];
            Bf[slot] = f;
        }
    }

    // ---- biases as MFMA C-operands (constant across a tile's 4 C-regs) ----
    const float brz  = bih[GG + j]      + bhh[GG + j];
    const float bzz  = bih[GG + 64 + j] + bhh[GG + 64 + j];
    const float bin_ = bih[GG + 128 + j];
    const float bhn_ = bhh[GG + 128 + j];
    const f32x4 BIASr = {brz,  brz,  brz,  brz };
    const f32x4 BIASz = {bzz,  bzz,  bzz,  bzz };
    const f32x4 BIASi = {bin_, bin_, bin_, bin_};
    const f32x4 BIASh = {bhn_, bhn_, bhn_, bhn_};

    // ---- init buf0: zero h region, stage x_0 ----
    const int xrow = tid >> 3;          // 0..31
    const int xkc  = (tid & 7) * 8;     // half offset 0,8,...,56
    {
        *(u32x4*)(lds_h + xrow * AK + 64 + xkc) = (u32x4){0u, 0u, 0u, 0u};

        const float* xsrc = x + ((size_t)(bb * TT) * NN + n0 + xrow) * HH + xkc;
        float4 p0 = *(const float4*)xsrc;
        float4 p1 = *(const float4*)(xsrc + 4);
        u32x4 w = {pkh2(p0.x, p0.y), pkh2(p0.z, p0.w),
                   pkh2(p1.x, p1.y), pkh2(p1.z, p1.w)};
        *(u32x4*)(lds_h + xrow * AK + xkc) = w;
    }

    float hreg[2][4];
    #pragma unroll
    for (int m = 0; m < 2; ++m)
        #pragma unroll
        for (int r = 0; r < 4; ++r) hreg[m][r] = 0.f;

    __syncthreads();   // buf0 ready for t=0

    for (int t = 0; t < TT; ++t) {
        _Float16* cur = lds_h + (t & 1) * HBUF;
        _Float16* nxt = lds_h + ((t & 1) ^ 1) * HBUF;
        const bool hasNext = (t + 1 < TT);

        // prefetch x_{t+1} (HBM/L3 latency hides under the MFMA phase)
        float4 p0, p1;
        if (hasNext) {
            const float* xsrc =
                x + ((size_t)(bb * TT + t + 1) * NN + n0 + xrow) * HH + xkc;
            p0 = *(const float4*)xsrc;
            p1 = *(const float4*)(xsrc + 4);
        }

        // ===== MFMA: 4 gate chains x 2 m-tiles, bias as C of first MFMA =====
        f32x4 acc[2][4];
        __builtin_amdgcn_s_setprio(1);
        #pragma unroll
        for (int m = 0; m < 2; ++m) {
            const _Float16* ab = cur + (m * 16 + c0) * AK + rq * 8;
            h8 A0 = *(const h8*)(ab);
            h8 A1 = *(const h8*)(ab + 32);
            h8 A2 = *(const h8*)(ab + 64);
            h8 A3 = *(const h8*)(ab + 96);
            f32x4 ar = MF(A0, Bf[0], BIASr);
            ar       = MF(A1, Bf[1], ar);
            ar       = MF(A2, Bf[2], ar);
            ar       = MF(A3, Bf[3], ar);
            f32x4 az = MF(A0, Bf[4], BIASz);
            az       = MF(A1, Bf[5], az);
            az       = MF(A2, Bf[6], az);
            az       = MF(A3, Bf[7], az);
            f32x4 ai = MF(A0, Bf[8], BIASi);
            ai       = MF(A1, Bf[9], ai);
            f32x4 ah = MF(A2, Bf[10], BIASh);
            ah       = MF(A3, Bf[11], ah);
            acc[m][0] = ar; acc[m][1] = az; acc[m][2] = ai; acc[m][3] = ah;
        }
        __builtin_amdgcn_s_setprio(0);

        // ===== x(t+1) stage FIRST (vmcnt long drained; regs die early) =====
        if (hasNext) {
            u32x4 w = {pkh2(p0.x, p0.y), pkh2(p0.z, p0.w),
                       pkh2(p1.x, p1.y), pkh2(p1.z, p1.w)};
            *(u32x4*)(nxt + xrow * AK + xkc) = w;
        }

        // ===== epilogue: register-local gates; paired h dword writes =====
        #pragma unroll
        for (int r = 0; r < 4; ++r) {
            float rg0 = sigm(acc[0][0][r]);
            float zg0 = sigm(acc[0][1][r]);
            float ng0 = tanh_f(fmaf(rg0, acc[0][3][r], acc[0][2][r]));
            float hn0 = fmaf(zg0, hreg[0][r] - ng0, ng0);   // (1-z)n + z h
            hreg[0][r] = hn0;
            float rg1 = sigm(acc[1][0][r]);
            float zg1 = sigm(acc[1][1][r]);
            float ng1 = tanh_f(fmaf(rg1, acc[1][3][r], acc[1][2][r]));
            float hn1 = fmaf(zg1, hreg[1][r] - ng1, ng1);
            hreg[1][r] = hn1;
            if (hasNext) {
                // even lane writes m=0 row {j, j+1}; odd lane m=1 row {j-1, j}
                float s0 = __shfl_xor(hn0, 1);
                float s1 = __shfl_xor(hn1, 1);
                unsigned w = odd ? pkh2(s1, hn1) : pkh2(hn0, s0);
                const int row = (odd ? 16 : 0) + rq * 4 + r;
                *(unsigned*)(nxt + row * AK + 64 + (j & ~1)) = w;
            }
        }

        if (hasNext)
            __syncthreads();   // nxt (h_t + x_{t+1}) ready for step t+1
    }

    #pragma unroll
    for (int m = 0; m < 2; ++m)
        #pragma unroll
        for (int r = 0; r < 4; ++r)
            out[(size_t)(grow0 + m * 16 + rq * 4 + r) * HH + j] = hreg[m][r];
}

extern "C" void kernel_launch(void* const* d_in, const int* in_sizes, int n_in,
                              void* d_out, int out_size, void* d_ws, size_t ws_size,
                              hipStream_t stream) {
    const float* x   = (const float*)d_in[0];
    const float* Wih = (const float*)d_in[1];
    const float* Whh = (const float*)d_in[2];
    const float* bih = (const float*)d_in[3];
    const float* bhh = (const float*)d_in[4];
    float* out = (float*)d_out;

    const int lds_bytes = 2 * HBUF * (int)sizeof(_Float16);   // 17,408 B
    (void)hipFuncSetAttribute((const void*)ngru_mfma11,
                        hipFuncAttributeMaxDynamicSharedMemorySize, lds_bytes);

    dim3 grid(16384 / RPB);     // 512 blocks, 2 per CU
    dim3 block(NTHREADS);
    ngru_mfma11<<<grid, block, lds_bytes, stream>>>(x, Wih, Whh, bih, bhh, out);
}

// Round 12
// 68.749 us; speedup vs baseline: 1.7195x; 1.0784x over previous
//
#include <hip/hip_runtime.h>
#include <math.h>

// NGRU via MFMA, R12 = R9 structure with m-split waves (4 waves/SIMD).
// Only layer 1 of the 2 parallel GRU layers contributes (reference returns
// h_final[-1]); layer 0 is skipped.
//
// Shapes: x (64,48,256,64) f32; Wih/Whh (2,192,64); bih/bhh (2,192).
// rows = B*N = 16384 independent GRU sequences, T=48, H=64.
//
// Structure: 512 blocks x 512 threads (8 waves), 32 rows/block, 2 blocks/CU.
// Wave wv owns (m = wv>>2, j-slice = wv&3): 16 rows x 16 cols, all 4 gates
// -> register-local epilogue. Per wave: 4 ds_read_b128 + 12 MFMA + 4-row
// epilogue. vs R9: same block shape / barrier domains (R6 proved smaller
// domains regress), but 16 waves/CU = 4 waves/SIMD to fill the post-barrier
// ds_read latency, MFMA dep chains, and epilogue transcendental chain that
// 2 waves/SIMD left exposed (MfmaUtil 27%, step walltime ~2.6x pipe needs).
// fp16 made this possible: B-frags are 48 VGPR (was 96 in bf16-split), so
// the ~110-reg working set fits the 128-VGPR 4-waves/SIMD budget.
// amdgpu_waves_per_eu(4,4) pins the allocator (R4/R7 spill lesson:
// tripwire = WRITE_SIZE ballooning past 4 MB).
//
// A = [x_t | h_{t-1}] fp16 [32][AK=136], ping-ponged -> ONE barrier/step.
// x staged once in LDS (R7/R8/R10: per-wave x-in-registers loses).
// fp16 single-product MFMA (R9-verified: absmax unchanged).
// Chain order per accumulator identical to R9 -> bit-identical numerics.

#define TT 48
#define HH 64
#define GG 192
#define NN 256
#define RPB 32          // rows per block
#define NTHREADS 512    // 8 waves
#define AK 136          // A row stride in halfs (128 + 8 pad)
#define HBUF (RPB*AK)   // halfs per A buffer (4352)

typedef _Float16 h8 __attribute__((ext_vector_type(8)));   // 8 fp16 (4 VGPRs)
typedef __attribute__((ext_vector_type(4))) float f32x4;   // MFMA accum
typedef __attribute__((ext_vector_type(2))) unsigned u32x2;

__device__ __forceinline__ float sigm(float v) {
    return __builtin_amdgcn_rcpf(1.f + __expf(-v));
}
__device__ __forceinline__ float tanh_f(float v) {
    float a = fabsf(v);
    float e = __expf(2.f * a);
    float t = 1.f - 2.f * __builtin_amdgcn_rcpf(e + 1.f);
    return v < 0.f ? -t : t;
}
// pack 2 f32 -> dword of 2 fp16 (RNE)
__device__ __forceinline__ unsigned pkh2(float a, float b) {
    union { _Float16 h[2]; unsigned u; } c;
    c.h[0] = (_Float16)a; c.h[1] = (_Float16)b;
    return c.u;
}

#define MF(A, B, C) __builtin_amdgcn_mfma_f32_16x16x32_f16(A, B, C, 0, 0, 0)

__global__ __launch_bounds__(NTHREADS)
__attribute__((amdgpu_waves_per_eu(4, 4)))
void ngru_mfma12(const float* __restrict__ x,
                 const float* __restrict__ Wih,
                 const float* __restrict__ Whh,
                 const float* __restrict__ bih,
                 const float* __restrict__ bhh,
                 float* __restrict__ out)
{
    extern __shared__ __align__(16) _Float16 lds_h[];  // 2 x HBUF halfs

    const int tid  = threadIdx.x;
    const int lane = tid & 63;
    const int wv   = tid >> 6;          // wave 0..7
    const int m    = wv >> 2;           // row half: rows [16m, 16m+16)
    const int nw   = wv & 3;            // j slice [16nw, 16nw+16)
    const int c0   = lane & 15;         // C col within tile / A row index
    const int rq   = lane >> 4;         // quarter-wave
    const int j    = nw * 16 + c0;

    const int grow0 = blockIdx.x * RPB;
    const int bb    = grow0 / NN;
    const int n0    = grow0 % NN;

    const float* Wi = Wih + GG * HH;    // layer 1
    const float* Wh = Whh + GG * HH;

    // ---- B fragments (fp16) in registers: 12 kt-slots (j-dependent only;
    // waves nw and nw+4 hold identical copies, L2-cached loads) ----
    // slot: r -> 0..3 (kt0,1 = Wi; kt2,3 = Wh); z -> 4..7;
    //       gin -> 8,9 (Wi, A kt0,1); ghn -> 10,11 (Wh, A kt2,3).
    h8 Bf[12];
    #pragma unroll
    for (int g = 0; g < 4; ++g) {
        const int ktlo = (g == 3) ? 2 : 0;
        const int kthi = (g == 2) ? 2 : 4;
        #pragma unroll
        for (int kt = ktlo; kt < kthi; ++kt) {
            const int slot = (g < 2) ? g * 4 + kt : 8 + (g - 2) * 2 + (kt & 1);
            const bool isWi = (kt < 2);
            const int gbase = (g >= 2) ? 2 : g;
            const float* src = (isWi ? Wi : Wh)
                             + (gbase * 64 + j) * HH + (kt & 1) * 32 + rq * 8;
            h8 f;
            #pragma unroll
            for (int q = 0; q < 8; ++q) f[q] = (_Float16)src[q];
            Bf[slot] = f;
        }
    }

    // ---- biases (layer 1), r/z pre-summed; n biases stay separate ----
    const float brz  = bih[GG + j]      + bhh[GG + j];
    const float bzz  = bih[GG + 64 + j] + bhh[GG + 64 + j];
    const float bin_ = bih[GG + 128 + j];
    const float bhn_ = bhh[GG + 128 + j];

    // ---- init buf0: zero h region, stage x_0 (512 threads: 4 halfs each) ----
    const int xrow = tid >> 4;          // 0..31
    const int xc   = (tid & 15) * 4;    // half/float offset 0,4,...,60
    {
        *(u32x2*)(lds_h + xrow * AK + 64 + xc) = (u32x2){0u, 0u};
        const float* xsrc = x + ((size_t)(bb * TT) * NN + n0 + xrow) * HH + xc;
        float4 p = *(const float4*)xsrc;
        *(u32x2*)(lds_h + xrow * AK + xc) = (u32x2){pkh2(p.x, p.y), pkh2(p.z, p.w)};
    }

    float hreg[4];
    #pragma unroll
    for (int r = 0; r < 4; ++r) hreg[r] = 0.f;

    __syncthreads();   // buf0 ready for t=0

    for (int t = 0; t < TT; ++t) {
        _Float16* cur = lds_h + (t & 1) * HBUF;
        _Float16* nxt = lds_h + ((t & 1) ^ 1) * HBUF;
        const bool hasNext = (t + 1 < TT);

        // prefetch x_{t+1} (one float4/thread; latency hides under MFMAs)
        float4 p;
        if (hasNext)
            p = *(const float4*)(x + ((size_t)(bb * TT + t + 1) * NN
                                      + n0 + xrow) * HH + xc);

        // acc preloaded with biases (R9 pattern; constant across 4 C-regs)
        f32x4 acc0 = {brz,  brz,  brz,  brz };
        f32x4 acc1 = {bzz,  bzz,  bzz,  bzz };
        f32x4 acc2 = {bin_, bin_, bin_, bin_};
        f32x4 acc3 = {bhn_, bhn_, bhn_, bhn_};

        // ===== A reads (4 x ds_read_b128) + 12 MFMAs, R9 chain order =====
        const _Float16* ab = cur + (m * 16 + c0) * AK + rq * 8;
        h8 A0 = *(const h8*)(ab);
        h8 A1 = *(const h8*)(ab + 32);
        h8 A2 = *(const h8*)(ab + 64);
        h8 A3 = *(const h8*)(ab + 96);

        __builtin_amdgcn_s_setprio(1);
        acc0 = MF(A0, Bf[0], acc0);
        acc0 = MF(A1, Bf[1], acc0);
        acc0 = MF(A2, Bf[2], acc0);
        acc0 = MF(A3, Bf[3], acc0);
        acc1 = MF(A0, Bf[4], acc1);
        acc1 = MF(A1, Bf[5], acc1);
        acc1 = MF(A2, Bf[6], acc1);
        acc1 = MF(A3, Bf[7], acc1);
        acc2 = MF(A0, Bf[8], acc2);
        acc2 = MF(A1, Bf[9], acc2);
        acc3 = MF(A2, Bf[10], acc3);
        acc3 = MF(A3, Bf[11], acc3);
        __builtin_amdgcn_s_setprio(0);

        // ===== epilogue: register-local gates; h -> nxt buffer =====
        #pragma unroll
        for (int r = 0; r < 4; ++r) {
            const int row = m * 16 + rq * 4 + r;
            float rg = sigm(acc0[r]);
            float zg = sigm(acc1[r]);
            float ng = tanh_f(fmaf(rg, acc3[r], acc2[r]));
            float hn = fmaf(zg, hreg[r] - ng, ng);   // (1-z)n + z h
            hreg[r] = hn;
            if (hasNext)
                nxt[row * AK + 64 + j] = (_Float16)hn;   // ds_write_b16
        }

        if (hasNext) {
            *(u32x2*)(nxt + xrow * AK + xc) =
                (u32x2){pkh2(p.x, p.y), pkh2(p.z, p.w)};
            __syncthreads();   // nxt (h_t + x_{t+1}) ready for step t+1
        }
    }

    #pragma unroll
    for (int r = 0; r < 4; ++r)
        out[(size_t)(grow0 + m * 16 + rq * 4 + r) * HH + j] = hreg[r];
}

extern "C" void kernel_launch(void* const* d_in, const int* in_sizes, int n_in,
                              void* d_out, int out_size, void* d_ws, size_t ws_size,
                              hipStream_t stream) {
    const float* x   = (const float*)d_in[0];
    const float* Wih = (const float*)d_in[1];
    const float* Whh = (const float*)d_in[2];
    const float* bih = (const float*)d_in[3];
    const float* bhh = (const float*)d_in[4];
    float* out = (float*)d_out;

    const int lds_bytes = 2 * HBUF * (int)sizeof(_Float16);   // 17,408 B
    (void)hipFuncSetAttribute((const void*)ngru_mfma12,
                        hipFuncAttributeMaxDynamicSharedMemorySize, lds_bytes);

    dim3 grid(16384 / RPB);     // 512 blocks, 2 per CU
    dim3 block(NTHREADS);
    ngru_mfma12<<<grid, block, lds_bytes, stream>>>(x, Wih, Whh, bih, bhh, out);
}